// Round 8
// baseline (259.014 us; speedup 1.0000x reference)
//
#include <hip/hip_runtime.h>
#include <math.h>

// GAT layer, R8: LDS-free MFMA GEMM with attention dots fused as extra
// B-columns (a_s = x @ (W@att_src)); degree count unfused for attribution.
// Pipeline: memset -> wconv(+WS/WD) -> count -> gemm -> part -> apply ->
// bucket -> gather -> bnstats -> final.

constexpr float NEG_SLOPE = 0.2f;
constexpr float BN_EPS = 1e-5f;
constexpr float SM_EPS = 1e-16f;

typedef __attribute__((ext_vector_type(8))) short short8;   // 8 bf16 = 4 VGPRs
typedef __attribute__((ext_vector_type(4))) float f32x4;    // MFMA acc

__device__ inline unsigned bf16rne(float f) {
    unsigned b = __float_as_uint(f);
    return (b + 0x7fffu + ((b >> 16) & 1u)) >> 16;
}

// ---------------------------------------------------------------------------
// K0: blocks 0..63:  W [k][n] fp32 -> Wt rows 0..127 (bf16, [n][k]).
//     blocks 64..71: rows 128..143 = WS/WD: row 128+j, j<8: sum_f W[c][j*16+f]
//     *att_src[j][f]; j>=8 same with att_dst. (a_s = x @ WS by associativity)
// ---------------------------------------------------------------------------
__global__ __launch_bounds__(256) void k_wconv(
    const float* __restrict__ W, const float* __restrict__ att_src,
    const float* __restrict__ att_dst, unsigned short* __restrict__ Wtg)
{
    if (blockIdx.x < 64) {
        int idx = blockIdx.x * 256 + threadIdx.x;   // 16384 total
        int k = idx >> 7, nc = idx & 127;
        Wtg[nc * 128 + k] = (unsigned short)bf16rne(W[idx]);
    } else {
        // 8 blocks x 256 threads = 2048 = 128 c x 16 j
        int c = (blockIdx.x - 64) * 16 + (threadIdx.x >> 4);
        int j = threadIdx.x & 15;
        int h = j & 7;
        const float* att = (j < 8) ? att_src : att_dst;
        float v = 0.f;
#pragma unroll
        for (int f = 0; f < 16; ++f)
            v += W[c * 128 + h * 16 + f] * att[h * 16 + f];
        Wtg[(128 + j) * 128 + c] = (unsigned short)bf16rne(v);
    }
}

// ---------------------------------------------------------------------------
// K1: degree histogram over dst (self-loops are edges [E, E+n)).
// ---------------------------------------------------------------------------
__global__ __launch_bounds__(256) void k_count(
    const int* __restrict__ ei, int E, int n, int* __restrict__ deg)
{
    int e = blockIdx.x * 256 + threadIdx.x;
    if (e >= E + n) return;
    int dst = (e < E) ? ei[E + e] : (e - E);
    atomicAdd(&deg[dst], 1);
}

// ---------------------------------------------------------------------------
// K2: xp = x@W + a_s/a_d via one MFMA pass, no LDS, no barrier.
// 4 waves x 16-row stripes; B = Wt (144 x 128 bf16) from L2.
// ct tiles 0..7 -> xp cols; ct 8 -> [a_s | a_d].
// ---------------------------------------------------------------------------
__global__ __launch_bounds__(256) void k_gemm(
    const float* __restrict__ x, const unsigned short* __restrict__ Wtg,
    unsigned* __restrict__ xpb, float* __restrict__ a_s, float* __restrict__ a_d,
    int n)
{
    const int tid = threadIdx.x;
    const int lane = tid & 63;
    const int wid = tid >> 6;
    const int quad = lane >> 4;
    const int l16 = lane & 15;
    const int row = blockIdx.x * 64 + wid * 16 + l16;

    // A fragments: A[m=l16][k=kt*32+quad*8+j], f32->bf16 in-register.
    // Per instruction: 16 rows x 128B contiguous chunks — line-coalesced.
    const float4* x4 = (const float4*)x;
    short8 afrag[4];
#pragma unroll
    for (int kt = 0; kt < 4; ++kt) {
        float4 f0 = make_float4(0.f, 0.f, 0.f, 0.f), f1 = f0;
        if (row < n) {
            f0 = x4[(size_t)row * 32 + kt * 8 + quad * 2];
            f1 = x4[(size_t)row * 32 + kt * 8 + quad * 2 + 1];
        }
        short8 a;
        a[0] = (short)bf16rne(f0.x); a[1] = (short)bf16rne(f0.y);
        a[2] = (short)bf16rne(f0.z); a[3] = (short)bf16rne(f0.w);
        a[4] = (short)bf16rne(f1.x); a[5] = (short)bf16rne(f1.y);
        a[6] = (short)bf16rne(f1.z); a[7] = (short)bf16rne(f1.w);
        afrag[kt] = a;
    }

    f32x4 acc[9];
#pragma unroll
    for (int ct = 0; ct < 9; ++ct) acc[ct] = (f32x4){0.f, 0.f, 0.f, 0.f};

#pragma unroll
    for (int ct = 0; ct < 9; ++ct) {
#pragma unroll
        for (int kt = 0; kt < 4; ++kt) {
            short8 b = *(const short8*)&Wtg[(size_t)(ct * 16 + l16) * 128 + kt * 32 + quad * 8];
            acc[ct] = __builtin_amdgcn_mfma_f32_16x16x32_bf16(afrag[kt], b, acc[ct], 0, 0, 0);
        }
    }

    // epilogue: C layout col=l16, row=quad*4+r (rows of this wave's stripe)
    const int rowbase = blockIdx.x * 64 + wid * 16 + quad * 4;
#pragma unroll
    for (int ct = 0; ct < 8; ++ct) {
#pragma unroll
        for (int r = 0; r < 4; ++r) {
            float val = acc[ct][r];
            float other = __shfl_xor(val, 1);
            int orow = rowbase + r;
            if (!(lane & 1) && orow < n) {
                unsigned u = bf16rne(val) | (bf16rne(other) << 16);
                xpb[(size_t)orow * 64 + ct * 8 + (l16 >> 1)] = u;
            }
        }
    }
    // ct=8 tile: cols 0..7 = a_s heads, 8..15 = a_d heads — direct stores
#pragma unroll
    for (int r = 0; r < 4; ++r) {
        int orow = rowbase + r;
        if (orow < n) {
            float val = acc[8][r];
            if (l16 < 8) a_s[(size_t)orow * 8 + l16] = val;
            else         a_d[(size_t)orow * 8 + (l16 - 8)] = val;
        }
    }
}

// ---------------------------------------------------------------------------
// K3a: per-block partial sums of deg (256 elems/block).
// ---------------------------------------------------------------------------
__global__ __launch_bounds__(256) void k_part(
    const int* __restrict__ deg, int* __restrict__ partial, int n)
{
    __shared__ int wsum[4];
    int tid = threadIdx.x;
    int i = blockIdx.x * 256 + tid;
    int v = (i < n) ? deg[i] : 0;
#pragma unroll
    for (int off = 32; off > 0; off >>= 1) v += __shfl_down(v, off);
    if ((tid & 63) == 0) wsum[tid >> 6] = v;
    __syncthreads();
    if (tid == 0) partial[blockIdx.x] = wsum[0] + wsum[1] + wsum[2] + wsum[3];
}

// ---------------------------------------------------------------------------
// K3b: block offset via redundant wave-scan of partials; block-scan chunk;
// write row_ptr[i+1] and cursor[i] (=row_ptr[i]).
// ---------------------------------------------------------------------------
__global__ __launch_bounds__(256) void k_apply(
    const int* __restrict__ deg, const int* __restrict__ partial, int nb,
    int* __restrict__ row_ptr, int* __restrict__ cursor, int n)
{
    __shared__ int s_off;
    __shared__ int woff[4];
    const int tid = threadIdx.x;
    const int lane = tid & 63;
    const int wid = tid >> 6;

    if (wid == 0) {
        int carry = 0;
        int nseg = (nb + 63) / 64;
        for (int seg = 0; seg < nseg; ++seg) {
            int idx = seg * 64 + lane;
            int v = (idx < nb) ? partial[idx] : 0;
            int inc = v;
#pragma unroll
            for (int off = 1; off < 64; off <<= 1) {
                int t = __shfl_up(inc, off);
                if (lane >= off) inc += t;
            }
            if (idx == blockIdx.x) s_off = carry + inc - v;
            carry += __shfl(inc, 63);
        }
    }
    __syncthreads();

    int i = blockIdx.x * 256 + tid;
    int v = (i < n) ? deg[i] : 0;
    int inc = v;
#pragma unroll
    for (int off = 1; off < 64; off <<= 1) {
        int t = __shfl_up(inc, off);
        if (lane >= off) inc += t;
    }
    if (lane == 63) woff[wid] = inc;
    __syncthreads();
    if (tid == 0) {
        int a = 0;
#pragma unroll
        for (int w = 0; w < 4; ++w) { int t = woff[w]; woff[w] = a; a += t; }
    }
    __syncthreads();

    int excl = s_off + woff[wid] + inc - v;
    if (i < n) {
        cursor[i] = excl;
        row_ptr[i + 1] = excl + v;
    }
    if (i == 0) row_ptr[0] = 0;
}

// ---------------------------------------------------------------------------
// K4: bucket edges into CSR slots: slot = atomicAdd(&cursor[dst], 1).
// ---------------------------------------------------------------------------
__global__ __launch_bounds__(256) void k_bucket(
    const int* __restrict__ ei, int E, int n,
    int* __restrict__ cursor, int* __restrict__ csr_src)
{
    int e = blockIdx.x * 256 + threadIdx.x;
    if (e >= E + n) return;
    int src, dst;
    if (e < E) { src = ei[e]; dst = ei[E + e]; }
    else       { src = dst = e - E; }
    int slot = atomicAdd(&cursor[dst], 1);
    csr_src[slot] = src;
}

// ---------------------------------------------------------------------------
// K5: per-dst gather-aggregate, bf16 messages, 8-way edge unroll (MLP).
// ---------------------------------------------------------------------------
__global__ __launch_bounds__(256) void k_gather(
    const int* __restrict__ row_ptr, const int* __restrict__ csr_src,
    const float* __restrict__ a_s, const float* __restrict__ a_d,
    const unsigned* __restrict__ xpb, float* __restrict__ agg, int n)
{
    int node = blockIdx.x * 4 + (threadIdx.x >> 6);
    if (node >= n) return;
    int lane = threadIdx.x & 63;
    int h = lane >> 3;
    float ad = a_d[(size_t)node * 8 + h];
    int beg = row_ptr[node], end = row_ptr[node + 1];
    float acc0 = 0.f, acc1 = 0.f, s = 0.f;

    int slot = beg;
    for (; slot + 8 <= end; slot += 8) {
        int sx[8]; float w[8]; unsigned u[8];
#pragma unroll
        for (int j = 0; j < 8; ++j) sx[j] = csr_src[slot + j];
#pragma unroll
        for (int j = 0; j < 8; ++j) w[j] = a_s[(size_t)sx[j] * 8 + h];
#pragma unroll
        for (int j = 0; j < 8; ++j) u[j] = xpb[(size_t)sx[j] * 64 + lane];
#pragma unroll
        for (int j = 0; j < 8; ++j) {
            float v = w[j] + ad;
            v = v > 0.f ? v : NEG_SLOPE * v;
            float p = __expf(v);
            s += p;
            acc0 = fmaf(p, __uint_as_float(u[j] << 16), acc0);
            acc1 = fmaf(p, __uint_as_float(u[j] & 0xffff0000u), acc1);
        }
    }
    for (; slot < end; ++slot) {
        int src = csr_src[slot];
        float v = a_s[(size_t)src * 8 + h] + ad;
        v = v > 0.f ? v : NEG_SLOPE * v;
        float p = __expf(v);
        s += p;
        unsigned u = xpb[(size_t)src * 64 + lane];
        acc0 = fmaf(p, __uint_as_float(u << 16), acc0);
        acc1 = fmaf(p, __uint_as_float(u & 0xffff0000u), acc1);
    }
    float inv = 1.0f / (s + SM_EPS);
    *(float2*)&agg[(size_t)node * 128 + lane * 2] = make_float2(acc0 * inv, acc1 * inv);
}

// ---------------------------------------------------------------------------
// K6: per-channel sum / sum-of-squares of h = agg + bias (BN stats).
// ---------------------------------------------------------------------------
__global__ __launch_bounds__(256) void k_bnstats(
    const float* __restrict__ agg, const float* __restrict__ bias, int n,
    float* __restrict__ stats)
{
    int c = threadIdx.x & 127;
    int half = threadIdx.x >> 7;
    float b = bias[c];
    float s = 0.f, s2 = 0.f;
    for (int r = blockIdx.x * 2 + half; r < n; r += gridDim.x * 2) {
        float v = agg[(size_t)r * 128 + c] + b;
        s += v;
        s2 += v * v;
    }
    atomicAdd(&stats[c], s);
    atomicAdd(&stats[128 + c], s2);
}

// ---------------------------------------------------------------------------
// K7: finalize: BN (batch stats, biased var) + ReLU + residual.
// ---------------------------------------------------------------------------
__global__ __launch_bounds__(256) void k_final(
    const float* __restrict__ agg, const float* __restrict__ bias,
    const float* __restrict__ gamma, const float* __restrict__ beta,
    const float* __restrict__ stats, const float* __restrict__ x,
    float* __restrict__ out, int n)
{
    int i = blockIdx.x * 256 + threadIdx.x;
    int total = n * 128;
    if (i >= total) return;
    int c = i & 127;
    float invn = 1.0f / (float)n;
    float mean = stats[c] * invn;
    float var = stats[128 + c] * invn - mean * mean;
    float v = agg[i] + bias[c];
    v = (v - mean) * rsqrtf(var + BN_EPS) * gamma[c] + beta[c];
    v = fmaxf(v, 0.f);
    out[i] = v + x[i];
}

// ---------------------------------------------------------------------------
extern "C" void kernel_launch(void* const* d_in, const int* in_sizes, int n_in,
                              void* d_out, int out_size, void* d_ws, size_t ws_size,
                              hipStream_t stream)
{
    const float* x        = (const float*)d_in[0];
    const int*   ei       = (const int*)d_in[1];
    const float* W        = (const float*)d_in[2];
    const float* att_src  = (const float*)d_in[3];
    const float* att_dst  = (const float*)d_in[4];
    const float* bias     = (const float*)d_in[5];
    const float* bn_gamma = (const float*)d_in[6];
    const float* bn_beta  = (const float*)d_in[7];
    float* out = (float*)d_out;

    const int n = in_sizes[0] / 128;
    const int E = in_sizes[1] / 2;
    const int tot = E + n;
    const int nb = (n + 255) / 256;

    // workspace layout: stats and deg adjacent for a single memset
    float*          stats   = (float*)d_ws;                   // 256
    int*            deg     = (int*)(stats + 256);            // n
    int*            row_ptr = deg + n;                        // n+1
    int*            cursor  = row_ptr + n + 1;                // n
    int*            partial = cursor + n;                     // nb
    int*            csr_src = partial + nb;                   // E+n
    unsigned short* Wtg     = (unsigned short*)(csr_src + tot); // 144*128
    unsigned*       xpb     = (unsigned*)(Wtg + 144 * 128);   // n*64 (bf16 x2)
    float*          agg     = (float*)(xpb + (size_t)n * 64); // n*128
    float*          a_s     = agg + (size_t)n * 128;          // n*8
    float*          a_d     = a_s + (size_t)n * 8;            // n*8

    hipMemsetAsync(stats, 0, (256 + (size_t)n) * sizeof(int), stream);

    k_wconv<<<72, 256, 0, stream>>>(W, att_src, att_dst, Wtg);
    k_count<<<(tot + 255) / 256, 256, 0, stream>>>(ei, E, n, deg);
    k_gemm<<<(n + 63) / 64, 256, 0, stream>>>(x, Wtg, xpb, a_s, a_d, n);
    k_part<<<nb, 256, 0, stream>>>(deg, partial, n);
    k_apply<<<nb, 256, 0, stream>>>(deg, partial, nb, row_ptr, cursor, n);
    k_bucket<<<(tot + 255) / 256, 256, 0, stream>>>(ei, E, n, cursor, csr_src);
    k_gather<<<(n + 3) / 4, 256, 0, stream>>>(row_ptr, csr_src, a_s, a_d, xpb, agg, n);
    k_bnstats<<<320, 256, 0, stream>>>(agg, bias, n, stats);
    k_final<<<(n * 128 + 255) / 256, 256, 0, stream>>>(agg, bias, bn_gamma, bn_beta,
                                                       stats, x, out, n);
}